// Round 10
// baseline (241.062 us; speedup 1.0000x reference)
//
#include <hip/hip_runtime.h>
#include <hip/hip_bf16.h>
#include <math.h>

#define Nn 20000
#define Ee 320000
#define Dd 256
#define Hh 8
#define Cc 32
#define NEG_SLOPE 0.2f
#define LN_EPS 1e-5f

typedef __bf16 bf16x8 __attribute__((ext_vector_type(8)));
typedef float f32x4 __attribute__((ext_vector_type(4)));

__device__ __forceinline__ unsigned f2bf_rn(float f) {
    unsigned u = __float_as_uint(f);
    return (u + 0x7fffu + ((u >> 16) & 1u)) >> 16;
}

// ---------------- CSR build ----------------

__global__ void count_kernel(const int* __restrict__ ei, int* __restrict__ counts) {
    int e = blockIdx.x * 256 + threadIdx.x;
    if (e < Ee) atomicAdd(&counts[ei[Ee + e]], 1);
}

__global__ void __launch_bounds__(1024) scan_kernel(
        const int* __restrict__ counts, int* __restrict__ offs, int* __restrict__ gctr) {
    __shared__ int buf[1024];
    __shared__ int bbase;
    int tid = threadIdx.x;
    int i = blockIdx.x * 1024 + tid;
    int v = (i < Nn) ? counts[i] : 0;
    buf[tid] = v;
    __syncthreads();
    for (int off = 1; off < 1024; off <<= 1) {
        int t = (tid >= off) ? buf[tid - off] : 0;
        __syncthreads();
        buf[tid] += t;
        __syncthreads();
    }
    int incl = buf[tid];
    if (tid == 1023) bbase = atomicAdd(gctr, incl);
    __syncthreads();
    if (i < Nn) offs[i] = bbase + incl - v;
}

__global__ void fill_kernel(const int* __restrict__ ei, const float* __restrict__ eattr,
                            const int* __restrict__ offs,
                            int* __restrict__ cursor, int2* __restrict__ csr_meta) {
    int e = blockIdx.x * 256 + threadIdx.x;
    if (e < Ee) {
        int d = ei[Ee + e];
        int p = atomicAdd(&cursor[d], 1);
        int2 m;
        m.x = ei[e];
        m.y = __float_as_int(eattr[e]);
        csr_meta[offs[d] + p] = m;
    }
}

// ---------------- prep: cast X to bf16 ----------------

__global__ void cast_x_kernel(const float* __restrict__ x, unsigned short* __restrict__ Xb) {
    int i = blockIdx.x * 256 + threadIdx.x;
    float4 v = ((const float4*)x)[i];
    uint2 pk;
    pk.x = f2bf_rn(v.x) | (f2bf_rn(v.y) << 16);
    pk.y = f2bf_rn(v.z) | (f2bf_rn(v.w) << 16);
    ((uint2*)Xb)[i] = pk;
}

// ---------------- prep: W -> bf16 transposed  Wt[layer][512][256] ----------------

__global__ void prep_w_kernel(const float* __restrict__ Wl, const float* __restrict__ Wr,
                              unsigned short* __restrict__ Wt) {
    __shared__ float tile[64][65];
    int m = blockIdx.y;
    int layer = m >> 1;
    const float* W = ((m & 1) ? Wr : Wl) + (size_t)layer * 65536;
    int tk = (blockIdx.x >> 2) * 64, tn = (blockIdx.x & 3) * 64;
    int t = threadIdx.x;
    int lr = t >> 6, lc = t & 63;
#pragma unroll
    for (int i = 0; i < 16; ++i)
        tile[lr + i * 4][lc] = W[(size_t)(tk + lr + i * 4) * 256 + tn + lc];
    __syncthreads();
    unsigned short* dst = Wt + (size_t)m * 65536;
#pragma unroll
    for (int i = 0; i < 16; ++i)
        dst[(size_t)(tn + lr + i * 4) * 256 + tk + lc] = f2bf_rn(tile[lc][lr + i * 4]);
}

// ---------------- MFMA GEMM: XLR[M,512] = Xb[M,256] @ [Wl|Wr]^T + [bl|br] ----------------
// Tile 128x128, BK=64 staged as two BK=32 panels (proven round-6/8 shape).

__device__ __forceinline__ void gload16(const void* g, void* l) {
    __builtin_amdgcn_global_load_lds(
        (__attribute__((address_space(1))) void*)g,
        (__attribute__((address_space(3))) void*)l,
        16, 0, 0);
}

__global__ void __launch_bounds__(256) gemm_kernel(
        const unsigned short* __restrict__ Xb, const unsigned short* __restrict__ Wt,
        const float* __restrict__ bl, const float* __restrict__ br,
        unsigned short* __restrict__ XLR) {
    __shared__ short As[2][128 * 32];
    __shared__ short Bs[2][128 * 32];

    const int t = threadIdx.x;
    const int wave = t >> 6, lane = t & 63;
    const int ln = lane & 15, q = lane >> 4;
    const int wm = wave >> 1, wn = wave & 1;
    const int row0 = blockIdx.x * 128;
    const int col0 = blockIdx.y * 128;

    const int srow = t >> 2;
    const int skc = t & 3;

    f32x4 acc[4][4] = {};

    for (int k0 = 0; k0 < 256; k0 += 64) {
#pragma unroll
        for (int h = 0; h < 2; ++h) {
            int kh = k0 + h * 32;
#pragma unroll
            for (int p = 0; p < 2; ++p) {
                int ra = row0 + p * 64 + srow; if (ra > Nn - 1) ra = Nn - 1;
                gload16(Xb + (size_t)ra * 256 + kh + skc * 8, (char*)As[h] + p * 4096 + t * 16);
                int rb = col0 + p * 64 + srow;
                gload16(Wt + (size_t)rb * 256 + kh + skc * 8, (char*)Bs[h] + p * 4096 + t * 16);
            }
        }
        __syncthreads();
#pragma unroll
        for (int h = 0; h < 2; ++h) {
            bf16x8 af[4], bf[4];
#pragma unroll
            for (int i = 0; i < 4; ++i) {
                af[i] = *(const bf16x8*)(As[h] + (wm * 64 + i * 16 + ln) * 32 + q * 8);
                bf[i] = *(const bf16x8*)(Bs[h] + (wn * 64 + i * 16 + ln) * 32 + q * 8);
            }
#pragma unroll
            for (int i = 0; i < 4; ++i)
#pragma unroll
                for (int j = 0; j < 4; ++j)
                    acc[i][j] = __builtin_amdgcn_mfma_f32_16x16x32_bf16(af[i], bf[j], acc[i][j], 0, 0, 0);
        }
        __syncthreads();
    }

#pragma unroll
    for (int nt = 0; nt < 4; ++nt) {
        int col = col0 + wn * 64 + nt * 16 + ln;
        float bc = (col < 256) ? bl[col] : br[col - 256];
#pragma unroll
        for (int mt = 0; mt < 4; ++mt) {
#pragma unroll
            for (int r = 0; r < 4; ++r) {
                int row = row0 + wm * 64 + mt * 16 + q * 4 + r;
                if (row < Nn)
                    XLR[(size_t)row * 512 + col] = (unsigned short)f2bf_rn(acc[mt][nt][r] + bc);
            }
        }
    }
}

// ---------------- Fused node kernel ----------------
// 32 lanes per node (2 nodes/wave, 8 nodes/block). Lane owns 8 channels (16B).
// Plain softmax (logits O(1), shift-invariant). 4-edge software pipeline:
// 4 gathers in flight covers L2/L3 gather latency (~400 cyc) with ~2 iters
// of issue headroom. mode 0: residual fp32 x -> write bf16 Xb.
// mode 1: residual bf16 xin_b -> write fp32 out.

__global__ void __launch_bounds__(256) node_kernel(
        const unsigned short* __restrict__ XLR,
        const int* __restrict__ counts, const int* __restrict__ offs,
        const int2* __restrict__ csr_meta,
        const float* __restrict__ We, const float* __restrict__ att,
        const float* __restrict__ xin_f, const unsigned short* __restrict__ xin_b,
        const float* __restrict__ bias_out,
        const float* __restrict__ ln_g, const float* __restrict__ ln_b,
        float* __restrict__ out_f, unsigned short* __restrict__ out_b,
        int mode) {
    __shared__ int2 s_meta[8][32];
    int tid = threadIdx.x;
    int g = tid >> 5;
    int lane2 = tid & 31;
    int n = blockIdx.x * 8 + g;

    int base = offs[n];
    int deg = counts[n];
    int c0 = lane2 * 8;

    uint4 xrp = *(const uint4*)(XLR + (size_t)n * 512 + 256 + c0);
    float xr[8];
    xr[0] = __uint_as_float(xrp.x << 16); xr[1] = __uint_as_float(xrp.x & 0xffff0000u);
    xr[2] = __uint_as_float(xrp.y << 16); xr[3] = __uint_as_float(xrp.y & 0xffff0000u);
    xr[4] = __uint_as_float(xrp.z << 16); xr[5] = __uint_as_float(xrp.z & 0xffff0000u);
    xr[6] = __uint_as_float(xrp.w << 16); xr[7] = __uint_as_float(xrp.w & 0xffff0000u);

    float4 wv0 = *(const float4*)(We + c0);
    float4 wv1 = *(const float4*)(We + c0 + 4);
    float4 av0 = *(const float4*)(att + c0);
    float4 av1 = *(const float4*)(att + c0 + 4);
    float we[8] = {wv0.x, wv0.y, wv0.z, wv0.w, wv1.x, wv1.y, wv1.z, wv1.w};
    float at[8] = {av0.x, av0.y, av0.z, av0.w, av1.x, av1.y, av1.z, av1.w};

    float S = 0.f;
    float ac[8] = {};

    for (int b0 = 0; b0 < deg; b0 += 32) {
        int cnt = deg - b0; if (cnt > 32) cnt = 32;
        if (lane2 < cnt)
            s_meta[g][lane2] = csr_meta[base + b0 + lane2];
        __builtin_amdgcn_wave_barrier();

        uint4 raw[4];
        float ea[4];
#pragma unroll
        for (int j = 0; j < 4; ++j) {
            raw[j] = make_uint4(0, 0, 0, 0);
            ea[j] = 0.f;
            if (j < cnt) {
                int2 m = s_meta[g][j];
                ea[j] = __int_as_float(m.y);
                raw[j] = *(const uint4*)(XLR + (size_t)m.x * 512 + c0);
            }
        }

        for (int i = 0; i < cnt; i += 4) {
            uint4 cur[4];
            float ce[4];
#pragma unroll
            for (int j = 0; j < 4; ++j) { cur[j] = raw[j]; ce[j] = ea[j]; }
            // prefetch next 4 edges
#pragma unroll
            for (int j = 0; j < 4; ++j) {
                if (i + 4 + j < cnt) {
                    int2 m = s_meta[g][i + 4 + j];
                    ea[j] = __int_as_float(m.y);
                    raw[j] = *(const uint4*)(XLR + (size_t)m.x * 512 + c0);
                }
            }

            float xl[4][8];
            float p[4];
#pragma unroll
            for (int j = 0; j < 4; ++j) {
                xl[j][0] = __uint_as_float(cur[j].x << 16);
                xl[j][1] = __uint_as_float(cur[j].x & 0xffff0000u);
                xl[j][2] = __uint_as_float(cur[j].y << 16);
                xl[j][3] = __uint_as_float(cur[j].y & 0xffff0000u);
                xl[j][4] = __uint_as_float(cur[j].z << 16);
                xl[j][5] = __uint_as_float(cur[j].z & 0xffff0000u);
                xl[j][6] = __uint_as_float(cur[j].w << 16);
                xl[j][7] = __uint_as_float(cur[j].w & 0xffff0000u);
                float pj = 0.f;
#pragma unroll
                for (int k = 0; k < 8; ++k) {
                    float t = fmaf(ce[j], we[k], xl[j][k] + xr[k]);
                    pj = fmaf(fmaxf(t, NEG_SLOPE * t), at[k], pj);
                }
                p[j] = pj;
            }
#pragma unroll
            for (int j = 0; j < 4; ++j) p[j] += __shfl_xor(p[j], 1);
#pragma unroll
            for (int j = 0; j < 4; ++j) p[j] += __shfl_xor(p[j], 2);

            float w[4];
#pragma unroll
            for (int j = 0; j < 4; ++j) w[j] = __expf(p[j]);

#pragma unroll
            for (int j = 0; j < 4; ++j) {
                if (i + j < cnt) {
                    S += w[j];
#pragma unroll
                    for (int k = 0; k < 8; ++k) ac[k] = fmaf(w[j], xl[j][k], ac[k]);
                }
            }
        }
    }

    float inv = 1.f / (S + 1e-16f);
    float4 bo0 = *(const float4*)(bias_out + c0);
    float4 bo1 = *(const float4*)(bias_out + c0 + 4);
    float bo[8] = {bo0.x, bo0.y, bo0.z, bo0.w, bo1.x, bo1.y, bo1.z, bo1.w};
    float h[8];
#pragma unroll
    for (int j = 0; j < 8; ++j) h[j] = fmaf(ac[j], inv, bo[j]);

    float s1 = 0.f;
#pragma unroll
    for (int j = 0; j < 8; ++j) s1 += h[j];
    for (int off = 1; off < 32; off <<= 1) s1 += __shfl_xor(s1, off);
    float mu = s1 * (1.f / 256.f);
    float d[8];
    float s2 = 0.f;
#pragma unroll
    for (int j = 0; j < 8; ++j) { d[j] = h[j] - mu; s2 = fmaf(d[j], d[j], s2); }
    for (int off = 1; off < 32; off <<= 1) s2 += __shfl_xor(s2, off);
    float rstd = rsqrtf(s2 * (1.f / 256.f) + LN_EPS);

    float4 g0 = *(const float4*)(ln_g + c0);
    float4 g1 = *(const float4*)(ln_g + c0 + 4);
    float4 b0v = *(const float4*)(ln_b + c0);
    float4 b1v = *(const float4*)(ln_b + c0 + 4);
    float ga[8] = {g0.x, g0.y, g0.z, g0.w, g1.x, g1.y, g1.z, g1.w};
    float bb[8] = {b0v.x, b0v.y, b0v.z, b0v.w, b1v.x, b1v.y, b1v.z, b1v.w};

    float y[8];
#pragma unroll
    for (int j = 0; j < 8; ++j) {
        float v = fmaf(d[j] * rstd, ga[j], bb[j]);
        y[j] = v > 0.f ? v : (__expf(v) - 1.f);
    }

    float xi[8];
    if (mode == 0) {
        float4 x0 = *(const float4*)(xin_f + (size_t)n * 256 + c0);
        float4 x1 = *(const float4*)(xin_f + (size_t)n * 256 + c0 + 4);
        xi[0] = x0.x; xi[1] = x0.y; xi[2] = x0.z; xi[3] = x0.w;
        xi[4] = x1.x; xi[5] = x1.y; xi[6] = x1.z; xi[7] = x1.w;
    } else {
        uint4 xp = *(const uint4*)(xin_b + (size_t)n * 256 + c0);
        xi[0] = __uint_as_float(xp.x << 16); xi[1] = __uint_as_float(xp.x & 0xffff0000u);
        xi[2] = __uint_as_float(xp.y << 16); xi[3] = __uint_as_float(xp.y & 0xffff0000u);
        xi[4] = __uint_as_float(xp.z << 16); xi[5] = __uint_as_float(xp.z & 0xffff0000u);
        xi[6] = __uint_as_float(xp.w << 16); xi[7] = __uint_as_float(xp.w & 0xffff0000u);
    }
    float o[8];
#pragma unroll
    for (int j = 0; j < 8; ++j) o[j] = xi[j] + y[j];

    if (mode == 0) {
        uint4 pk;
        pk.x = f2bf_rn(o[0]) | (f2bf_rn(o[1]) << 16);
        pk.y = f2bf_rn(o[2]) | (f2bf_rn(o[3]) << 16);
        pk.z = f2bf_rn(o[4]) | (f2bf_rn(o[5]) << 16);
        pk.w = f2bf_rn(o[6]) | (f2bf_rn(o[7]) << 16);
        *(uint4*)(out_b + (size_t)n * 256 + c0) = pk;
    } else {
        float4 o0, o1;
        o0.x = o[0]; o0.y = o[1]; o0.z = o[2]; o0.w = o[3];
        o1.x = o[4]; o1.y = o[5]; o1.z = o[6]; o1.w = o[7];
        *(float4*)(out_f + (size_t)n * 256 + c0) = o0;
        *(float4*)(out_f + (size_t)n * 256 + c0 + 4) = o1;
    }
}

// ---------------- launch ----------------

extern "C" void kernel_launch(void* const* d_in, const int* in_sizes, int n_in,
                              void* d_out, int out_size, void* d_ws, size_t ws_size,
                              hipStream_t stream) {
    const float* x        = (const float*)d_in[0];
    const int*   ei       = (const int*)d_in[1];
    const float* eattr    = (const float*)d_in[2];
    const float* Wl       = (const float*)d_in[3];
    const float* bl       = (const float*)d_in[4];
    const float* Wr       = (const float*)d_in[5];
    const float* br       = (const float*)d_in[6];
    const float* We       = (const float*)d_in[7];
    const float* att      = (const float*)d_in[8];
    const float* bias_out = (const float*)d_in[9];
    const float* ln_g     = (const float*)d_in[10];
    const float* ln_b     = (const float*)d_in[11];
    float* out = (float*)d_out;

    char* ws = (char*)d_ws;
    size_t off = 0;
    unsigned short* Xb  = (unsigned short*)(ws + off); off += (size_t)Nn * Dd * 2;
    unsigned short* XLR = (unsigned short*)(ws + off); off += (size_t)Nn * 512 * 2;
    unsigned short* Wt = (unsigned short*)(ws + off); off += (size_t)4 * 256 * 256 * 2;
    int* counts   = (int*)(ws + off);   off += (size_t)Nn * 4;
    int* cursor   = (int*)(ws + off);   off += (size_t)Nn * 4;
    int* gctr     = (int*)(ws + off);   off += 16;
    int* offs     = (int*)(ws + off);   off += (size_t)(Nn + 4) * 4;
    int2* csr_meta = (int2*)(ws + off); off += (size_t)Ee * 8;

    hipMemsetAsync(counts, 0, 2 * (size_t)Nn * 4 + 16, stream);

    int egrid = (Ee + 255) / 256;
    count_kernel<<<egrid, 256, 0, stream>>>(ei, counts);
    scan_kernel<<<(Nn + 1023) / 1024, 1024, 0, stream>>>(counts, offs, gctr);
    fill_kernel<<<egrid, 256, 0, stream>>>(ei, eattr, offs, cursor, csr_meta);
    prep_w_kernel<<<dim3(16, 4), 256, 0, stream>>>(Wl, Wr, Wt);
    cast_x_kernel<<<(Nn * Dd / 4 + 255) / 256, 256, 0, stream>>>(x, Xb);

    for (int l = 0; l < 2; ++l) {
        gemm_kernel<<<dim3((Nn + 127) / 128, 4), 256, 0, stream>>>(
            Xb, Wt + (size_t)l * 2 * 65536, bl + (size_t)l * Dd, br + (size_t)l * Dd, XLR);
        node_kernel<<<Nn / 8, 256, 0, stream>>>(
            XLR, counts, offs, csr_meta,
            We + (size_t)l * Dd, att + (size_t)l * Dd,
            x, Xb, bias_out + (size_t)l * Dd,
            ln_g + (size_t)l * Dd, ln_b + (size_t)l * Dd,
            out, Xb, l);
    }
}

// Round 11
// 229.899 us; speedup vs baseline: 1.0486x; 1.0486x over previous
//
#include <hip/hip_runtime.h>
#include <hip/hip_bf16.h>
#include <math.h>

#define Nn 20000
#define Ee 320000
#define Dd 256
#define Hh 8
#define Cc 32
#define NEG_SLOPE 0.2f
#define LN_EPS 1e-5f

typedef __bf16 bf16x8 __attribute__((ext_vector_type(8)));
typedef float f32x4 __attribute__((ext_vector_type(4)));

__device__ __forceinline__ unsigned f2bf_rn(float f) {
    unsigned u = __float_as_uint(f);
    return (u + 0x7fffu + ((u >> 16) & 1u)) >> 16;
}

// ---------------- merged prep: count + cast_x + prep_w ----------------
// blocks [0,1250): edge count atomics
// blocks [1250,6250): cast x -> bf16 (one float4/thread)
// blocks [6250,6314): W transpose+cast (64 tiles: 16 per matrix x 4 matrices)

__global__ void __launch_bounds__(256) prep_kernel(
        const int* __restrict__ ei, int* __restrict__ counts,
        const float* __restrict__ x, unsigned short* __restrict__ Xb,
        const float* __restrict__ Wl, const float* __restrict__ Wr,
        unsigned short* __restrict__ Wt) {
    __shared__ float tile[64][65];
    int b = blockIdx.x;
    if (b < 1250) {
        int e = b * 256 + threadIdx.x;
        if (e < Ee) atomicAdd(&counts[ei[Ee + e]], 1);
    } else if (b < 6250) {
        int i = (b - 1250) * 256 + threadIdx.x;
        float4 v = ((const float4*)x)[i];
        uint2 pk;
        pk.x = f2bf_rn(v.x) | (f2bf_rn(v.y) << 16);
        pk.y = f2bf_rn(v.z) | (f2bf_rn(v.w) << 16);
        ((uint2*)Xb)[i] = pk;
    } else {
        int bb = b - 6250;          // 0..63
        int m = bb >> 4;            // matrix index: layer*2 + (0:Wl,1:Wr)
        int tile_id = bb & 15;
        int layer = m >> 1;
        const float* W = ((m & 1) ? Wr : Wl) + (size_t)layer * 65536;
        int tk = (tile_id >> 2) * 64, tn = (tile_id & 3) * 64;
        int t = threadIdx.x;
        int lr = t >> 6, lc = t & 63;
#pragma unroll
        for (int i = 0; i < 16; ++i)
            tile[lr + i * 4][lc] = W[(size_t)(tk + lr + i * 4) * 256 + tn + lc];
        __syncthreads();
        unsigned short* dst = Wt + (size_t)m * 65536;
#pragma unroll
        for (int i = 0; i < 16; ++i)
            dst[(size_t)(tn + lr + i * 4) * 256 + tk + lc] = f2bf_rn(tile[lc][lr + i * 4]);
    }
}

// ---------------- CSR scan + fill ----------------

__global__ void __launch_bounds__(1024) scan_kernel(
        const int* __restrict__ counts, int* __restrict__ offs, int* __restrict__ gctr) {
    __shared__ int buf[1024];
    __shared__ int bbase;
    int tid = threadIdx.x;
    int i = blockIdx.x * 1024 + tid;
    int v = (i < Nn) ? counts[i] : 0;
    buf[tid] = v;
    __syncthreads();
    for (int off = 1; off < 1024; off <<= 1) {
        int t = (tid >= off) ? buf[tid - off] : 0;
        __syncthreads();
        buf[tid] += t;
        __syncthreads();
    }
    int incl = buf[tid];
    if (tid == 1023) bbase = atomicAdd(gctr, incl);
    __syncthreads();
    if (i < Nn) offs[i] = bbase + incl - v;
}

__global__ void fill_kernel(const int* __restrict__ ei, const float* __restrict__ eattr,
                            const int* __restrict__ offs,
                            int* __restrict__ cursor, int2* __restrict__ csr_meta) {
    int e = blockIdx.x * 256 + threadIdx.x;
    if (e < Ee) {
        int d = ei[Ee + e];
        int p = atomicAdd(&cursor[d], 1);
        int2 m;
        m.x = ei[e];
        m.y = __float_as_int(eattr[e]);
        csr_meta[offs[d] + p] = m;
    }
}

// ---------------- MFMA GEMM: XLR[M,512] = Xb[M,256] @ [Wl|Wr]^T + [bl|br] ----------------
// Tile 128x128, BK=64 as two BK=32 panels (proven r6/r8 shape).
// Grid (4,157): col-blocks of the same row-tile have consecutive IDs so their
// shared A staging is dispatch-proximal (L2/L3 temporal locality).

__device__ __forceinline__ void gload16(const void* g, void* l) {
    __builtin_amdgcn_global_load_lds(
        (__attribute__((address_space(1))) void*)g,
        (__attribute__((address_space(3))) void*)l,
        16, 0, 0);
}

__global__ void __launch_bounds__(256) gemm_kernel(
        const unsigned short* __restrict__ Xb, const unsigned short* __restrict__ Wt,
        const float* __restrict__ bl, const float* __restrict__ br,
        unsigned short* __restrict__ XLR) {
    __shared__ short As[2][128 * 32];
    __shared__ short Bs[2][128 * 32];

    const int t = threadIdx.x;
    const int wave = t >> 6, lane = t & 63;
    const int ln = lane & 15, q = lane >> 4;
    const int wm = wave >> 1, wn = wave & 1;
    const int row0 = blockIdx.y * 128;
    const int col0 = blockIdx.x * 128;

    const int srow = t >> 2;
    const int skc = t & 3;

    f32x4 acc[4][4] = {};

    for (int k0 = 0; k0 < 256; k0 += 64) {
#pragma unroll
        for (int h = 0; h < 2; ++h) {
            int kh = k0 + h * 32;
#pragma unroll
            for (int p = 0; p < 2; ++p) {
                int ra = row0 + p * 64 + srow; if (ra > Nn - 1) ra = Nn - 1;
                gload16(Xb + (size_t)ra * 256 + kh + skc * 8, (char*)As[h] + p * 4096 + t * 16);
                int rb = col0 + p * 64 + srow;
                gload16(Wt + (size_t)rb * 256 + kh + skc * 8, (char*)Bs[h] + p * 4096 + t * 16);
            }
        }
        __syncthreads();
#pragma unroll
        for (int h = 0; h < 2; ++h) {
            bf16x8 af[4], bf[4];
#pragma unroll
            for (int i = 0; i < 4; ++i) {
                af[i] = *(const bf16x8*)(As[h] + (wm * 64 + i * 16 + ln) * 32 + q * 8);
                bf[i] = *(const bf16x8*)(Bs[h] + (wn * 64 + i * 16 + ln) * 32 + q * 8);
            }
#pragma unroll
            for (int i = 0; i < 4; ++i)
#pragma unroll
                for (int j = 0; j < 4; ++j)
                    acc[i][j] = __builtin_amdgcn_mfma_f32_16x16x32_bf16(af[i], bf[j], acc[i][j], 0, 0, 0);
        }
        __syncthreads();
    }

#pragma unroll
    for (int nt = 0; nt < 4; ++nt) {
        int col = col0 + wn * 64 + nt * 16 + ln;
        float bc = (col < 256) ? bl[col] : br[col - 256];
#pragma unroll
        for (int mt = 0; mt < 4; ++mt) {
#pragma unroll
            for (int r = 0; r < 4; ++r) {
                int row = row0 + wm * 64 + mt * 16 + q * 4 + r;
                if (row < Nn)
                    XLR[(size_t)row * 512 + col] = (unsigned short)f2bf_rn(acc[mt][nt][r] + bc);
            }
        }
    }
}

// ---------------- Fused node kernel (r8 measured-best form) ----------------
// 32 lanes per node (2 nodes/wave, 8 nodes/block). Lane owns 8 channels (16B),
// head = lane2>>2. Plain softmax (logits O(1), shift-invariant). 2-edge unroll.
// mode 0: residual fp32 x -> write bf16 Xb.  mode 1: residual bf16 -> fp32 out.

__global__ void __launch_bounds__(256) node_kernel(
        const unsigned short* __restrict__ XLR,
        const int* __restrict__ counts, const int* __restrict__ offs,
        const int2* __restrict__ csr_meta,
        const float* __restrict__ We, const float* __restrict__ att,
        const float* __restrict__ xin_f, const unsigned short* __restrict__ xin_b,
        const float* __restrict__ bias_out,
        const float* __restrict__ ln_g, const float* __restrict__ ln_b,
        float* __restrict__ out_f, unsigned short* __restrict__ out_b,
        int mode) {
    __shared__ int2 s_meta[8][32];
    int tid = threadIdx.x;
    int g = tid >> 5;
    int lane2 = tid & 31;
    int n = blockIdx.x * 8 + g;

    int base = offs[n];
    int deg = counts[n];
    int c0 = lane2 * 8;

    uint4 xrp = *(const uint4*)(XLR + (size_t)n * 512 + 256 + c0);
    float xr[8];
    xr[0] = __uint_as_float(xrp.x << 16); xr[1] = __uint_as_float(xrp.x & 0xffff0000u);
    xr[2] = __uint_as_float(xrp.y << 16); xr[3] = __uint_as_float(xrp.y & 0xffff0000u);
    xr[4] = __uint_as_float(xrp.z << 16); xr[5] = __uint_as_float(xrp.z & 0xffff0000u);
    xr[6] = __uint_as_float(xrp.w << 16); xr[7] = __uint_as_float(xrp.w & 0xffff0000u);

    float4 wv0 = *(const float4*)(We + c0);
    float4 wv1 = *(const float4*)(We + c0 + 4);
    float4 av0 = *(const float4*)(att + c0);
    float4 av1 = *(const float4*)(att + c0 + 4);
    float we[8] = {wv0.x, wv0.y, wv0.z, wv0.w, wv1.x, wv1.y, wv1.z, wv1.w};
    float at[8] = {av0.x, av0.y, av0.z, av0.w, av1.x, av1.y, av1.z, av1.w};

    float S = 0.f;
    float ac[8] = {};

    for (int b0 = 0; b0 < deg; b0 += 32) {
        int cnt = deg - b0; if (cnt > 32) cnt = 32;
        if (lane2 < cnt)
            s_meta[g][lane2] = csr_meta[base + b0 + lane2];
        __builtin_amdgcn_wave_barrier();

        float eaA = 0.f, eaB = 0.f;
        uint4 rawA = {0, 0, 0, 0}, rawB = {0, 0, 0, 0};
        {
            int2 m = s_meta[g][0];
            eaA = __int_as_float(m.y);
            rawA = *(const uint4*)(XLR + (size_t)m.x * 512 + c0);
        }
        if (cnt > 1) {
            int2 m = s_meta[g][1];
            eaB = __int_as_float(m.y);
            rawB = *(const uint4*)(XLR + (size_t)m.x * 512 + c0);
        }

        for (int i = 0; i < cnt; i += 2) {
            uint4 cA = rawA; float eA = eaA;
            uint4 cB = rawB; float eB = eaB;
            int rem = cnt - i;
            if (i + 2 < cnt) {
                int2 m = s_meta[g][i + 2];
                eaA = __int_as_float(m.y);
                rawA = *(const uint4*)(XLR + (size_t)m.x * 512 + c0);
            }
            if (i + 3 < cnt) {
                int2 m = s_meta[g][i + 3];
                eaB = __int_as_float(m.y);
                rawB = *(const uint4*)(XLR + (size_t)m.x * 512 + c0);
            }

            float xlA[8], xlB[8];
            xlA[0] = __uint_as_float(cA.x << 16); xlA[1] = __uint_as_float(cA.x & 0xffff0000u);
            xlA[2] = __uint_as_float(cA.y << 16); xlA[3] = __uint_as_float(cA.y & 0xffff0000u);
            xlA[4] = __uint_as_float(cA.z << 16); xlA[5] = __uint_as_float(cA.z & 0xffff0000u);
            xlA[6] = __uint_as_float(cA.w << 16); xlA[7] = __uint_as_float(cA.w & 0xffff0000u);
            xlB[0] = __uint_as_float(cB.x << 16); xlB[1] = __uint_as_float(cB.x & 0xffff0000u);
            xlB[2] = __uint_as_float(cB.y << 16); xlB[3] = __uint_as_float(cB.y & 0xffff0000u);
            xlB[4] = __uint_as_float(cB.z << 16); xlB[5] = __uint_as_float(cB.z & 0xffff0000u);
            xlB[6] = __uint_as_float(cB.w << 16); xlB[7] = __uint_as_float(cB.w & 0xffff0000u);

            float pA = 0.f, pB = 0.f;
#pragma unroll
            for (int k = 0; k < 8; ++k) {
                float tA = fmaf(eA, we[k], xlA[k] + xr[k]);
                float tB = fmaf(eB, we[k], xlB[k] + xr[k]);
                pA = fmaf(fmaxf(tA, NEG_SLOPE * tA), at[k], pA);
                pB = fmaf(fmaxf(tB, NEG_SLOPE * tB), at[k], pB);
            }
            pA += __shfl_xor(pA, 1);
            pB += __shfl_xor(pB, 1);
            pA += __shfl_xor(pA, 2);
            pB += __shfl_xor(pB, 2);

            float wA = __expf(pA);
            float wB = __expf(pB);

            S += wA;
#pragma unroll
            for (int k = 0; k < 8; ++k) ac[k] = fmaf(wA, xlA[k], ac[k]);
            if (rem > 1) {
                S += wB;
#pragma unroll
                for (int k = 0; k < 8; ++k) ac[k] = fmaf(wB, xlB[k], ac[k]);
            }
        }
    }

    float inv = 1.f / (S + 1e-16f);
    float4 bo0 = *(const float4*)(bias_out + c0);
    float4 bo1 = *(const float4*)(bias_out + c0 + 4);
    float bo[8] = {bo0.x, bo0.y, bo0.z, bo0.w, bo1.x, bo1.y, bo1.z, bo1.w};
    float h[8];
#pragma unroll
    for (int j = 0; j < 8; ++j) h[j] = fmaf(ac[j], inv, bo[j]);

    float s1 = 0.f;
#pragma unroll
    for (int j = 0; j < 8; ++j) s1 += h[j];
    for (int off = 1; off < 32; off <<= 1) s1 += __shfl_xor(s1, off);
    float mu = s1 * (1.f / 256.f);
    float d[8];
    float s2 = 0.f;
#pragma unroll
    for (int j = 0; j < 8; ++j) { d[j] = h[j] - mu; s2 = fmaf(d[j], d[j], s2); }
    for (int off = 1; off < 32; off <<= 1) s2 += __shfl_xor(s2, off);
    float rstd = rsqrtf(s2 * (1.f / 256.f) + LN_EPS);

    float4 g0 = *(const float4*)(ln_g + c0);
    float4 g1 = *(const float4*)(ln_g + c0 + 4);
    float4 b0v = *(const float4*)(ln_b + c0);
    float4 b1v = *(const float4*)(ln_b + c0 + 4);
    float ga[8] = {g0.x, g0.y, g0.z, g0.w, g1.x, g1.y, g1.z, g1.w};
    float bb[8] = {b0v.x, b0v.y, b0v.z, b0v.w, b1v.x, b1v.y, b1v.z, b1v.w};

    float y[8];
#pragma unroll
    for (int j = 0; j < 8; ++j) {
        float v = fmaf(d[j] * rstd, ga[j], bb[j]);
        y[j] = v > 0.f ? v : (__expf(v) - 1.f);
    }

    float xi[8];
    if (mode == 0) {
        float4 x0 = *(const float4*)(xin_f + (size_t)n * 256 + c0);
        float4 x1 = *(const float4*)(xin_f + (size_t)n * 256 + c0 + 4);
        xi[0] = x0.x; xi[1] = x0.y; xi[2] = x0.z; xi[3] = x0.w;
        xi[4] = x1.x; xi[5] = x1.y; xi[6] = x1.z; xi[7] = x1.w;
    } else {
        uint4 xp = *(const uint4*)(xin_b + (size_t)n * 256 + c0);
        xi[0] = __uint_as_float(xp.x << 16); xi[1] = __uint_as_float(xp.x & 0xffff0000u);
        xi[2] = __uint_as_float(xp.y << 16); xi[3] = __uint_as_float(xp.y & 0xffff0000u);
        xi[4] = __uint_as_float(xp.z << 16); xi[5] = __uint_as_float(xp.z & 0xffff0000u);
        xi[6] = __uint_as_float(xp.w << 16); xi[7] = __uint_as_float(xp.w & 0xffff0000u);
    }
    float o[8];
#pragma unroll
    for (int j = 0; j < 8; ++j) o[j] = xi[j] + y[j];

    if (mode == 0) {
        uint4 pk;
        pk.x = f2bf_rn(o[0]) | (f2bf_rn(o[1]) << 16);
        pk.y = f2bf_rn(o[2]) | (f2bf_rn(o[3]) << 16);
        pk.z = f2bf_rn(o[4]) | (f2bf_rn(o[5]) << 16);
        pk.w = f2bf_rn(o[6]) | (f2bf_rn(o[7]) << 16);
        *(uint4*)(out_b + (size_t)n * 256 + c0) = pk;
    } else {
        float4 o0, o1;
        o0.x = o[0]; o0.y = o[1]; o0.z = o[2]; o0.w = o[3];
        o1.x = o[4]; o1.y = o[5]; o1.z = o[6]; o1.w = o[7];
        *(float4*)(out_f + (size_t)n * 256 + c0) = o0;
        *(float4*)(out_f + (size_t)n * 256 + c0 + 4) = o1;
    }
}

// ---------------- launch ----------------

extern "C" void kernel_launch(void* const* d_in, const int* in_sizes, int n_in,
                              void* d_out, int out_size, void* d_ws, size_t ws_size,
                              hipStream_t stream) {
    const float* x        = (const float*)d_in[0];
    const int*   ei       = (const int*)d_in[1];
    const float* eattr    = (const float*)d_in[2];
    const float* Wl       = (const float*)d_in[3];
    const float* bl       = (const float*)d_in[4];
    const float* Wr       = (const float*)d_in[5];
    const float* br       = (const float*)d_in[6];
    const float* We       = (const float*)d_in[7];
    const float* att      = (const float*)d_in[8];
    const float* bias_out = (const float*)d_in[9];
    const float* ln_g     = (const float*)d_in[10];
    const float* ln_b     = (const float*)d_in[11];
    float* out = (float*)d_out;

    char* ws = (char*)d_ws;
    size_t off = 0;
    unsigned short* Xb  = (unsigned short*)(ws + off); off += (size_t)Nn * Dd * 2;
    unsigned short* XLR = (unsigned short*)(ws + off); off += (size_t)Nn * 512 * 2;
    unsigned short* Wt = (unsigned short*)(ws + off); off += (size_t)4 * 256 * 256 * 2;
    int* counts   = (int*)(ws + off);   off += (size_t)Nn * 4;
    int* cursor   = (int*)(ws + off);   off += (size_t)Nn * 4;
    int* gctr     = (int*)(ws + off);   off += 16;
    int* offs     = (int*)(ws + off);   off += (size_t)(Nn + 4) * 4;
    int2* csr_meta = (int2*)(ws + off); off += (size_t)Ee * 8;

    hipMemsetAsync(counts, 0, 2 * (size_t)Nn * 4 + 16, stream);

    // merged: count (1250) + cast_x (5000) + prep_w (64)
    prep_kernel<<<6314, 256, 0, stream>>>(ei, counts, x, Xb, Wl, Wr, Wt);
    scan_kernel<<<(Nn + 1023) / 1024, 1024, 0, stream>>>(counts, offs, gctr);
    fill_kernel<<<(Ee + 255) / 256, 256, 0, stream>>>(ei, eattr, offs, cursor, csr_meta);

    for (int l = 0; l < 2; ++l) {
        gemm_kernel<<<dim3(4, (Nn + 127) / 128), 256, 0, stream>>>(
            Xb, Wt + (size_t)l * 2 * 65536, bl + (size_t)l * Dd, br + (size_t)l * Dd, XLR);
        node_kernel<<<Nn / 8, 256, 0, stream>>>(
            XLR, counts, offs, csr_meta,
            We + (size_t)l * Dd, att + (size_t)l * Dd,
            x, Xb, bias_out + (size_t)l * Dd,
            ln_g + (size_t)l * Dd, ln_b + (size_t)l * Dd,
            out, Xb, l);
    }
}